// Round 1
// baseline (1188.513 us; speedup 1.0000x reference)
//
#include <hip/hip_runtime.h>

typedef unsigned short u16;
typedef short short8v __attribute__((ext_vector_type(8)));
typedef u16 u16x8 __attribute__((ext_vector_type(8)));
typedef float f32x4 __attribute__((ext_vector_type(4)));

#define D_ 1024
#define E_ 8
#define H_ 5632
#define H2_ 11264
#define N_ 8192
#define C_ 1280

// d_out layout (floats): y[N*D], aux[1], top[N], keep[N]
#define OUT_AUX ((size_t)N_ * D_)
#define OUT_TOP (OUT_AUX + 1)
#define OUT_KEEP (OUT_TOP + N_)

// workspace byte offsets
#define WS_ACC 0         // 9 floats: sum_probs[8], sum_z2
#define WS_CNT 64        // 8 ints
#define WS_TOP 4096      // N ints
#define WS_TFS 40960     // E*C ints (token for slot)
#define WS_XE  131072    // E*C*D bf16
#define WS_H   21102592  // E*C*H bf16

__device__ __forceinline__ u16 f2bf(float f) {
  __bf16 b = (__bf16)f;
  return __builtin_bit_cast(u16, b);
}

__device__ __forceinline__ void async16(void* l, const void* g) {
  __builtin_amdgcn_global_load_lds(
      (const __attribute__((address_space(1))) unsigned int*)g,
      (__attribute__((address_space(3))) unsigned int*)l, 16, 0, 0);
}

__global__ void k_zero(float* acc) {
  if (threadIdx.x < 9) acc[threadIdx.x] = 0.f;
}

// ---------------- K1: router -----------------------------------------------
// 1 wave per token; W_g staged in LDS; fp32 logits; first-max argmax.
__global__ __launch_bounds__(256) void k_router(const float* __restrict__ x,
                                                const float* __restrict__ Wg,
                                                float* __restrict__ acc_ws,
                                                int* __restrict__ top_out) {
  __shared__ float wg[E_ * D_];  // 32 KB
  __shared__ float blk_probs[E_];
  __shared__ float blk_z2;
  int t = threadIdx.x;
#pragma unroll
  for (int i = 0; i < 8; ++i) {
    int idx = i * 256 + t;  // 2048 float4 total
    ((float4*)wg)[idx] = ((const float4*)Wg)[idx];
  }
  if (t < E_) blk_probs[t] = 0.f;
  if (t == 8) blk_z2 = 0.f;
  __syncthreads();

  int wave = t >> 6, lane = t & 63;
  int n = blockIdx.x * 4 + wave;
  const float4* xr = (const float4*)(x + (size_t)n * D_);
  float4 xv[4];
#pragma unroll
  for (int j = 0; j < 4; ++j) xv[j] = xr[j * 64 + lane];

  float lg[E_];
#pragma unroll
  for (int e = 0; e < E_; ++e) {
    const float4* wr4 = (const float4*)(wg + e * D_);
    float a = 0.f;
#pragma unroll
    for (int j = 0; j < 4; ++j) {
      float4 wv = wr4[j * 64 + lane];
      a += xv[j].x * wv.x + xv[j].y * wv.y + xv[j].z * wv.z + xv[j].w * wv.w;
    }
    lg[e] = a;
  }
#pragma unroll
  for (int e = 0; e < E_; ++e) {
    float v = lg[e];
#pragma unroll
    for (int off = 32; off; off >>= 1) v += __shfl_xor(v, off);
    lg[e] = v;
  }
  // softmax stats (all lanes redundantly)
  float m = lg[0];
  int best = 0;
#pragma unroll
  for (int e = 1; e < E_; ++e)
    if (lg[e] > m) { m = lg[e]; best = e; }
  float s = 0.f;
#pragma unroll
  for (int e = 0; e < E_; ++e) s += __expf(lg[e] - m);
  float z = m + __logf(s);
  if (lane == 0) {
    top_out[n] = best;
    atomicAdd(&blk_z2, z * z);
    float inv = 1.f / s;
#pragma unroll
    for (int e = 0; e < E_; ++e) atomicAdd(&blk_probs[e], __expf(lg[e] - m) * inv);
  }
  __syncthreads();
  if (t < E_) atomicAdd(&acc_ws[t], blk_probs[t]);
  else if (t == 8) atomicAdd(&acc_ws[8], blk_z2);
}

// ---------------- K2: stable per-expert prefix scan -------------------------
__global__ __launch_bounds__(1024) void k_scan(const int* __restrict__ top,
                                               const float* __restrict__ acc_ws,
                                               int* __restrict__ cnt_out,
                                               int* __restrict__ tfs,
                                               float* __restrict__ out) {
  __shared__ int waveSums[16][E_];
  __shared__ int waveOff[16][E_];
  __shared__ int totals[E_];
  int t = threadIdx.x;
  int wave = t >> 6, lane = t & 63;
  int base = t * 8;
  int tops[8];
#pragma unroll
  for (int i = 0; i < 8; ++i) tops[i] = top[base + i];
  int cnt[E_], excl[E_];
#pragma unroll
  for (int e = 0; e < E_; ++e) {
    int c = 0;
#pragma unroll
    for (int i = 0; i < 8; ++i) c += (tops[i] == e) ? 1 : 0;
    cnt[e] = c;
  }
#pragma unroll
  for (int e = 0; e < E_; ++e) {
    int inc = cnt[e];
    for (int off = 1; off < 64; off <<= 1) {
      int u = __shfl_up(inc, off);
      if (lane >= off) inc += u;
    }
    if (lane == 63) waveSums[wave][e] = inc;
    excl[e] = inc - cnt[e];
  }
  __syncthreads();
  if (wave == 0 && lane < 16) {
#pragma unroll
    for (int e = 0; e < E_; ++e) {
      int v = waveSums[lane][e];
      int inc = v;
      for (int off = 1; off < 16; off <<= 1) {
        int u = __shfl_up(inc, off);
        if (lane >= off) inc += u;
      }
      waveOff[lane][e] = inc - v;
      if (lane == 15) totals[e] = inc;
    }
  }
  __syncthreads();
  int run[E_];
#pragma unroll
  for (int e = 0; e < E_; ++e) run[e] = waveOff[wave][e] + excl[e];
#pragma unroll
  for (int i = 0; i < 8; ++i) {
    int n = base + i;
    int e = tops[i];
    int p = 0;
#pragma unroll
    for (int e2 = 0; e2 < E_; ++e2) {  // static indexing (avoid scratch)
      if (e2 == e) { p = run[e2]; run[e2] = p + 1; }
    }
    int keep = (p < C_) ? 1 : 0;
    out[OUT_TOP + n] = (float)e;
    out[OUT_KEEP + n] = (float)keep;
    if (keep) tfs[e * C_ + p] = n;
  }
  if (t < E_) cnt_out[t] = totals[t];
  if (t == 0) {
    float bal = 0.f;
    for (int e = 0; e < E_; ++e)
      bal += (acc_ws[e] * (1.f / N_)) * ((float)totals[e] * (1.f / N_));
    out[OUT_AUX] = bal * 0.01f * (float)E_ + acc_ws[8] * (1.f / N_) * 0.001f;
  }
}

// ---------------- K3: gather x rows -> xe (bf16) ----------------------------
__global__ __launch_bounds__(256) void k_gather(const float* __restrict__ x,
                                                const int* __restrict__ tfs,
                                                const int* __restrict__ cnt,
                                                u16* __restrict__ xe) {
  int c = blockIdx.x, e = blockIdx.y;
  if (c >= cnt[e]) return;
  int n = tfs[e * C_ + c];
  float4 v = ((const float4*)(x + (size_t)n * D_))[threadIdx.x];
  ushort4 o;
  o.x = f2bf(v.x); o.y = f2bf(v.y); o.z = f2bf(v.z); o.w = f2bf(v.w);
  ((ushort4*)(xe + ((size_t)e * C_ + c) * D_))[threadIdx.x] = o;
}

// ---------------- K3b: zero output rows for dropped tokens ------------------
__global__ __launch_bounds__(256) void k_zero_dropped(const float* __restrict__ keepf,
                                                      float* __restrict__ out) {
  int n = blockIdx.x;
  if (keepf[n] != 0.f) return;
  float4 z; z.x = z.y = z.z = z.w = 0.f;
  ((float4*)(out + (size_t)n * D_))[threadIdx.x] = z;
}

// ---------------- K4: GEMM1 fused GLU: h = silu(xe.W13g^T) * (xe.W13u^T) ----
// tile: 128 slots x 64 h-cols (g tile + u tile), BK=32, 4 waves (2x2), dbuf LDS
__global__ __launch_bounds__(256) void k_gemm1(const u16* __restrict__ xe,
                                               const float* __restrict__ W13,
                                               const int* __restrict__ cnt,
                                               u16* __restrict__ hbuf) {
  int e = blockIdx.z;
  int m0 = blockIdx.y * 128;
  if (m0 >= cnt[e]) return;
  int j0 = blockIdx.x * 64;
  __shared__ u16 lds[16384];  // A dbuf 2*4096 elems, B dbuf 2*4096 elems
  int t = threadIdx.x;
  int wave = t >> 6, lane = t & 63;

  // A staging via global_load_lds (xe already bf16, rows contiguous)
  const char* abase = (const char*)(xe + ((size_t)e * C_ + m0) * D_);
  int o1 = wave * 1024 + lane * 16;  // linear byte in 8KB tile
  int o2 = o1 + 4096;
  const char* ag1 = abase + (size_t)(o1 >> 6) * (D_ * 2) + (o1 & 63);
  const char* ag2 = abase + (size_t)(o2 >> 6) * (D_ * 2) + (o2 & 63);

  // B staging: fp32 -> bf16 in registers; rows 0-63 = g (W13 row j0+r),
  // rows 64-127 = u (W13 row H+j0+r)
  int brow = t >> 1, bhalf = t & 1;
  int grow = (brow < 64) ? (j0 + brow) : (H_ + j0 + (brow - 64));
  const float* bsrc = W13 + (size_t)e * H2_ * D_ + (size_t)grow * D_ + bhalf * 16;

  int wr = wave >> 1, wc = wave & 1;
  int frow = lane & 15;
  int koff = (lane >> 4) * 8;

  f32x4 accg[4][2] = {}, accu[4][2] = {};

  auto stage = [&](int p, int ks) {
    u16* Ap = lds + p * 4096;
    async16(Ap + wave * 512, ag1 + ks * 64);
    async16(Ap + 2048 + wave * 512, ag2 + ks * 64);
    const float4* s4 = (const float4*)(bsrc + (size_t)ks * 32);
    float4 f0 = s4[0], f1 = s4[1], f2 = s4[2], f3 = s4[3];
    u16x8 u0, u1;
    u0[0] = f2bf(f0.x); u0[1] = f2bf(f0.y); u0[2] = f2bf(f0.z); u0[3] = f2bf(f0.w);
    u0[4] = f2bf(f1.x); u0[5] = f2bf(f1.y); u0[6] = f2bf(f1.z); u0[7] = f2bf(f1.w);
    u1[0] = f2bf(f2.x); u1[1] = f2bf(f2.y); u1[2] = f2bf(f2.z); u1[3] = f2bf(f2.w);
    u1[4] = f2bf(f3.x); u1[5] = f2bf(f3.y); u1[6] = f2bf(f3.z); u1[7] = f2bf(f3.w);
    u16* bd = lds + 8192 + p * 4096 + brow * 32 + bhalf * 16;
    *(u16x8*)bd = u0;
    *((u16x8*)bd + 1) = u1;
  };

  auto compute = [&](int p) {
    const u16* Ap = lds + p * 4096;
    const u16* Bp = lds + 8192 + p * 4096;
    short8v a[4], bg[2], bu[2];
#pragma unroll
    for (int mi = 0; mi < 4; ++mi)
      a[mi] = *(const short8v*)(Ap + (wr * 64 + mi * 16 + frow) * 32 + koff);
#pragma unroll
    for (int ni = 0; ni < 2; ++ni) {
      int col = wc * 32 + ni * 16 + frow;
      bg[ni] = *(const short8v*)(Bp + col * 32 + koff);
      bu[ni] = *(const short8v*)(Bp + (64 + col) * 32 + koff);
    }
#pragma unroll
    for (int mi = 0; mi < 4; ++mi)
#pragma unroll
      for (int ni = 0; ni < 2; ++ni) {
        accg[mi][ni] = __builtin_amdgcn_mfma_f32_16x16x32_bf16(a[mi], bg[ni], accg[mi][ni], 0, 0, 0);
        accu[mi][ni] = __builtin_amdgcn_mfma_f32_16x16x32_bf16(a[mi], bu[ni], accu[mi][ni], 0, 0, 0);
      }
  };

  stage(0, 0);
  __syncthreads();
  for (int ks = 0; ks < 32; ++ks) {
    int p = ks & 1;
    if (ks + 1 < 32) stage(p ^ 1, ks + 1);
    compute(p);
    __syncthreads();
  }

  u16* hd = hbuf + ((size_t)e * C_ + m0) * H_ + j0;
  int rbase = wr * 64 + (lane >> 4) * 4;
  int cbase = wc * 32 + (lane & 15);
#pragma unroll
  for (int mi = 0; mi < 4; ++mi)
#pragma unroll
    for (int ni = 0; ni < 2; ++ni)
#pragma unroll
      for (int i = 0; i < 4; ++i) {
        float g = accg[mi][ni][i];
        float u = accu[mi][ni][i];
        float h = (g / (1.f + __expf(-g))) * u;
        hd[(size_t)(rbase + mi * 16 + i) * H_ + (cbase + ni * 16)] = f2bf(h);
      }
}

// ---------------- K5: GEMM2 + scatter: out[tok] = h.W2^T --------------------
// tile: 128 slots x 128 d-cols, BK=32 over K=H=5632, dbuf LDS
__global__ __launch_bounds__(256) void k_gemm2(const u16* __restrict__ hbuf,
                                               const float* __restrict__ W2,
                                               const int* __restrict__ cnt,
                                               const int* __restrict__ tfs,
                                               float* __restrict__ out) {
  int e = blockIdx.z;
  int m0 = blockIdx.y * 128;
  int cnte = cnt[e];
  if (m0 >= cnte) return;
  int d0 = blockIdx.x * 128;
  __shared__ u16 lds[16384];
  __shared__ int toks[128];
  int t = threadIdx.x;
  if (t < 128) toks[t] = (m0 + t < cnte) ? tfs[e * C_ + m0 + t] : -1;
  int wave = t >> 6, lane = t & 63;

  const char* abase = (const char*)(hbuf + ((size_t)e * C_ + m0) * H_);
  int o1 = wave * 1024 + lane * 16;
  int o2 = o1 + 4096;
  const char* ag1 = abase + (size_t)(o1 >> 6) * (H_ * 2) + (o1 & 63);
  const char* ag2 = abase + (size_t)(o2 >> 6) * (H_ * 2) + (o2 & 63);

  int brow = t >> 1, bhalf = t & 1;
  const float* bsrc = W2 + (size_t)e * D_ * H_ + (size_t)(d0 + brow) * H_ + bhalf * 16;

  int wr = wave >> 1, wc = wave & 1;
  int frow = lane & 15;
  int koff = (lane >> 4) * 8;

  f32x4 acc[4][4] = {};

  auto stage = [&](int p, int ks) {
    u16* Ap = lds + p * 4096;
    async16(Ap + wave * 512, ag1 + (size_t)ks * 64);
    async16(Ap + 2048 + wave * 512, ag2 + (size_t)ks * 64);
    const float4* s4 = (const float4*)(bsrc + (size_t)ks * 32);
    float4 f0 = s4[0], f1 = s4[1], f2 = s4[2], f3 = s4[3];
    u16x8 u0, u1;
    u0[0] = f2bf(f0.x); u0[1] = f2bf(f0.y); u0[2] = f2bf(f0.z); u0[3] = f2bf(f0.w);
    u0[4] = f2bf(f1.x); u0[5] = f2bf(f1.y); u0[6] = f2bf(f1.z); u0[7] = f2bf(f1.w);
    u1[0] = f2bf(f2.x); u1[1] = f2bf(f2.y); u1[2] = f2bf(f2.z); u1[3] = f2bf(f2.w);
    u1[4] = f2bf(f3.x); u1[5] = f2bf(f3.y); u1[6] = f2bf(f3.z); u1[7] = f2bf(f3.w);
    u16* bd = lds + 8192 + p * 4096 + brow * 32 + bhalf * 16;
    *(u16x8*)bd = u0;
    *((u16x8*)bd + 1) = u1;
  };

  auto compute = [&](int p) {
    const u16* Ap = lds + p * 4096;
    const u16* Bp = lds + 8192 + p * 4096;
    short8v a[4], b[4];
#pragma unroll
    for (int mi = 0; mi < 4; ++mi)
      a[mi] = *(const short8v*)(Ap + (wr * 64 + mi * 16 + frow) * 32 + koff);
#pragma unroll
    for (int ni = 0; ni < 4; ++ni)
      b[ni] = *(const short8v*)(Bp + (wc * 64 + ni * 16 + frow) * 32 + koff);
#pragma unroll
    for (int mi = 0; mi < 4; ++mi)
#pragma unroll
      for (int ni = 0; ni < 4; ++ni)
        acc[mi][ni] = __builtin_amdgcn_mfma_f32_16x16x32_bf16(a[mi], b[ni], acc[mi][ni], 0, 0, 0);
  };

  stage(0, 0);
  __syncthreads();
  for (int ks = 0; ks < 176; ++ks) {
    int p = ks & 1;
    if (ks + 1 < 176) stage(p ^ 1, ks + 1);
    compute(p);
    __syncthreads();
  }

  int rb = wr * 64 + (lane >> 4) * 4;
#pragma unroll
  for (int mi = 0; mi < 4; ++mi)
#pragma unroll
    for (int i = 0; i < 4; ++i) {
      int tok = toks[rb + mi * 16 + i];
      if (tok >= 0) {
        float* od = out + (size_t)tok * D_ + d0 + wc * 64 + (lane & 15);
#pragma unroll
        for (int ni = 0; ni < 4; ++ni) od[ni * 16] = acc[mi][ni][i];
      }
    }
}

// ---------------------------------------------------------------------------
extern "C" void kernel_launch(void* const* d_in, const int* in_sizes, int n_in,
                              void* d_out, int out_size, void* d_ws, size_t ws_size,
                              hipStream_t stream) {
  (void)in_sizes; (void)n_in; (void)out_size; (void)ws_size;
  const float* x   = (const float*)d_in[0];
  const float* Wg  = (const float*)d_in[1];
  const float* W13 = (const float*)d_in[2];
  const float* W2  = (const float*)d_in[3];
  float* out = (float*)d_out;
  char* ws = (char*)d_ws;
  float* acc = (float*)(ws + WS_ACC);
  int* cnt   = (int*)(ws + WS_CNT);
  int* top   = (int*)(ws + WS_TOP);
  int* tfs   = (int*)(ws + WS_TFS);
  u16* xe    = (u16*)(ws + WS_XE);
  u16* hb    = (u16*)(ws + WS_H);

  k_zero<<<1, 64, 0, stream>>>(acc);
  k_router<<<N_ / 4, 256, 0, stream>>>(x, Wg, acc, top);
  k_scan<<<1, 1024, 0, stream>>>(top, acc, cnt, tfs, out);
  k_gather<<<dim3(C_, E_), 256, 0, stream>>>(x, tfs, cnt, xe);
  k_zero_dropped<<<N_, 256, 0, stream>>>(out + OUT_KEEP, out);
  k_gemm1<<<dim3(H_ / 64, C_ / 128, E_), 256, 0, stream>>>(xe, W13, cnt, hb);
  k_gemm2<<<dim3(D_ / 128, C_ / 128, E_), 256, 0, stream>>>(hb, W2, cnt, tfs, out);
}